// Round 1
// baseline (631.068 us; speedup 1.0000x reference)
//
#include <hip/hip_runtime.h>

#define N_V 35709
#define N_F 70789
#define NR  (3*N_V)   // 107127
#define NB  64

// ws layout (floats):
//   rotM : NB*9   = 576    @ 0
//   gm   : NB*27  = 1728   @ 576
//   ctrS : 144*NB = 9216   @ 2304   (id+ex coeffs, [j][b])
//   ctrT : 80*NB  = 5120   @ 11520  (tex coeffs, [j][b])
//   shape: NB*NR           @ 16640  (pre-rotation face_shape, [b][3N])
#define WS_ROT   0
#define WS_GM    576
#define WS_CTRS  2304
#define WS_CTRT  11520
#define WS_SHAPE 16640

__global__ __launch_bounds__(64) void k_setup(
    const float* __restrict__ coeffs, const float* __restrict__ init_lit,
    float* __restrict__ rotM, float* __restrict__ gm,
    float* __restrict__ ctrS, float* __restrict__ ctrT)
{
    int b = threadIdx.x;
    const float* cb = coeffs + b * 257;

    // rotation: M = Rz@Ry@Rx ; reference rot = M^T, used as row-vec @ rot == M @ col-vec
    float ax = cb[224], ay = cb[225], az = cb[226];
    float cx = cosf(ax), sx = sinf(ax);
    float cy = cosf(ay), sy = sinf(ay);
    float cz = cosf(az), sz = sinf(az);
    float m[9];
    m[0] = cz * cy;
    m[1] = cz * sy * sx - sz * cx;
    m[2] = sz * sx + cz * sy * cx;
    m[3] = sz * cy;
    m[4] = cz * cx + sz * sy * sx;
    m[5] = sz * sy * cx - cz * sx;
    m[6] = -sy;
    m[7] = cy * sx;
    m[8] = cy * cx;
#pragma unroll
    for (int k = 0; k < 9; k++) rotM[b * 9 + k] = m[k];

    // lighting matrix g[b][k][c] = gamma[b][c*9+k] + init_lit[k]
#pragma unroll
    for (int k = 0; k < 9; k++) {
        float il = init_lit[k];
#pragma unroll
        for (int c = 0; c < 3; c++)
            gm[b * 27 + k * 3 + c] = cb[227 + c * 9 + k] + il;
    }

    // coeff transpose to [j][b] so GEMM reads them at wave-uniform addresses
    for (int j = 0; j < 144; j++) ctrS[j * 64 + b] = cb[j];        // id(80)+ex(64)
    for (int j = 0; j < 80; j++)  ctrT[j * 64 + b] = cb[144 + j];  // tex
}

__global__ __launch_bounds__(64) void k_gemm(
    const float* __restrict__ idBase, const float* __restrict__ exBase,
    const float* __restrict__ texBase, const float* __restrict__ meanshape,
    const float* __restrict__ meantex,
    const float* __restrict__ ctrS, const float* __restrict__ ctrT,
    float* __restrict__ shape_out,   // ws, [b][NR]
    float* __restrict__ tex_out)     // = face_color region of d_out, [b][NR]
{
    int i = blockIdx.x * 64 + threadIdx.x;
    int iv = (i < NR) ? i : (NR - 1);
    const bool ok = (i < NR);

    float2 acc[32];
#pragma unroll
    for (int q = 0; q < 32; q++) { acc[q].x = 0.f; acc[q].y = 0.f; }

    // ---- shape: idBase (80) + exBase (64), coeffs ctrS[0..143] ----
    {
        const float4* r4 = (const float4*)(idBase + (size_t)iv * 80);
#pragma unroll 2
        for (int jq = 0; jq < 20; jq++) {
            float4 a4 = r4[jq];
            float as[4] = {a4.x, a4.y, a4.z, a4.w};
#pragma unroll
            for (int s = 0; s < 4; s++) {
                float a = as[s];
                const float2* cp = (const float2*)(ctrS + (jq * 4 + s) * 64);
#pragma unroll
                for (int q = 0; q < 32; q++) {
                    float2 c = cp[q];
                    acc[q].x += a * c.x;
                    acc[q].y += a * c.y;
                }
            }
        }
        const float4* e4 = (const float4*)(exBase + (size_t)iv * 64);
#pragma unroll 2
        for (int jq = 0; jq < 16; jq++) {
            float4 a4 = e4[jq];
            float as[4] = {a4.x, a4.y, a4.z, a4.w};
#pragma unroll
            for (int s = 0; s < 4; s++) {
                float a = as[s];
                const float2* cp = (const float2*)(ctrS + (80 + jq * 4 + s) * 64);
#pragma unroll
                for (int q = 0; q < 32; q++) {
                    float2 c = cp[q];
                    acc[q].x += a * c.x;
                    acc[q].y += a * c.y;
                }
            }
        }
        float ms = meanshape[iv];
        if (ok) {
#pragma unroll
            for (int q = 0; q < 32; q++) {
                shape_out[(size_t)(2 * q)     * NR + i] = acc[q].x + ms;
                shape_out[(size_t)(2 * q + 1) * NR + i] = acc[q].y + ms;
            }
        }
    }

    // ---- texture: texBase (80), coeffs ctrT ----
#pragma unroll
    for (int q = 0; q < 32; q++) { acc[q].x = 0.f; acc[q].y = 0.f; }
    {
        const float4* t4 = (const float4*)(texBase + (size_t)iv * 80);
#pragma unroll 2
        for (int jq = 0; jq < 20; jq++) {
            float4 a4 = t4[jq];
            float as[4] = {a4.x, a4.y, a4.z, a4.w};
#pragma unroll
            for (int s = 0; s < 4; s++) {
                float a = as[s];
                const float2* cp = (const float2*)(ctrT + (jq * 4 + s) * 64);
#pragma unroll
                for (int q = 0; q < 32; q++) {
                    float2 c = cp[q];
                    acc[q].x += a * c.x;
                    acc[q].y += a * c.y;
                }
            }
        }
        float mt = meantex[iv];
        const float inv255 = 1.0f / 255.0f;
        if (ok) {
#pragma unroll
            for (int q = 0; q < 32; q++) {
                tex_out[(size_t)(2 * q)     * NR + i] = (acc[q].x + mt) * inv255;
                tex_out[(size_t)(2 * q + 1) * NR + i] = (acc[q].y + mt) * inv255;
            }
        }
    }
}

__global__ __launch_bounds__(256) void k_vertex(
    const float* __restrict__ shape,   // ws [b][NR]
    const float* __restrict__ rotM,    // ws [b][9]
    const float* __restrict__ gm,      // ws [b][27]
    const float* __restrict__ coeffs,  // for trans
    const int* __restrict__ point_buf, const int* __restrict__ face_buf,
    float* __restrict__ out_vertex,    // d_out[0]
    float* __restrict__ out_color)     // d_out[1]; holds texture on entry
{
    int b = blockIdx.y;
    int v = blockIdx.x * 256 + threadIdx.x;
    if (v >= N_V) return;

    const float* S = shape + (size_t)b * NR;
    float m0 = rotM[b * 9 + 0], m1 = rotM[b * 9 + 1], m2 = rotM[b * 9 + 2];
    float m3 = rotM[b * 9 + 3], m4 = rotM[b * 9 + 4], m5 = rotM[b * 9 + 5];
    float m6 = rotM[b * 9 + 6], m7 = rotM[b * 9 + 7], m8 = rotM[b * 9 + 8];
    float tx = coeffs[b * 257 + 254], ty = coeffs[b * 257 + 255], tz = coeffs[b * 257 + 256];

    float sx0 = S[3 * v], sy0 = S[3 * v + 1], sz0 = S[3 * v + 2];
    float vx = m0 * sx0 + m1 * sy0 + m2 * sz0 + tx;
    float vy = m3 * sx0 + m4 * sy0 + m5 * sz0 + ty;
    float vz = m6 * sx0 + m7 * sy0 + m8 * sz0 + tz;

    size_t ob = (size_t)b * NR + 3 * (size_t)v;
    out_vertex[ob]     = vx;
    out_vertex[ob + 1] = vy;
    out_vertex[ob + 2] = 10.0f - vz;

    // vertex normal: sum of 8 normalized face normals (pre-rotation shape)
    float nx = 0.f, ny = 0.f, nz = 0.f;
    const int* pb = point_buf + (size_t)v * 8;
#pragma unroll
    for (int k = 0; k < 8; k++) {
        int f = pb[k];
        if (f < N_F) {
            int i0 = face_buf[f * 3], i1 = face_buf[f * 3 + 1], i2 = face_buf[f * 3 + 2];
            float p0x = S[3 * i0], p0y = S[3 * i0 + 1], p0z = S[3 * i0 + 2];
            float p1x = S[3 * i1], p1y = S[3 * i1 + 1], p1z = S[3 * i1 + 2];
            float p2x = S[3 * i2], p2y = S[3 * i2 + 1], p2z = S[3 * i2 + 2];
            float e1x = p0x - p1x, e1y = p0y - p1y, e1z = p0z - p1z;
            float e2x = p1x - p2x, e2y = p1y - p2y, e2z = p1z - p2z;
            float cx = e1y * e2z - e1z * e2y;
            float cy = e1z * e2x - e1x * e2z;
            float cz = e1x * e2y - e1y * e2x;
            float l = sqrtf(cx * cx + cy * cy + cz * cz);
            float inv = 1.0f / fmaxf(l, 1e-12f);
            nx += cx * inv; ny += cy * inv; nz += cz * inv;
        }
    }
    float l = sqrtf(nx * nx + ny * ny + nz * nz);
    float inv = 1.0f / fmaxf(l, 1e-12f);
    nx *= inv; ny *= inv; nz *= inv;

    // rotate normal
    float rx = m0 * nx + m1 * ny + m2 * nz;
    float ry = m3 * nx + m4 * ny + m5 * nz;
    float rz = m6 * nx + m7 * ny + m8 * nz;

    // SH basis
    const float A0C0 = 0.8862269254527580f;   // pi / sqrt(4pi)
    const float A1C1 = 1.7724538509055159f;   // sqrt(pi)
    const float A2C2 = 2.4270323912f;         // (2pi/sqrt(8)) * 3 sqrt(5)/sqrt(12pi)
    const float C6   = 0.7006239022f;         // 0.5*A2C2/sqrt(3)
    const float C8   = 1.2135161956f;         // 0.5*A2C2
    float Y0 = A0C0;
    float Y1 = -A1C1 * ry;
    float Y2 =  A1C1 * rz;
    float Y3 = -A1C1 * rx;
    float Y4 =  A2C2 * rx * ry;
    float Y5 = -A2C2 * ry * rz;
    float Y6 =  C6 * (3.f * rz * rz - 1.f);
    float Y7 = -A2C2 * rx * rz;
    float Y8 =  C8 * (rx * rx - ry * ry);

    const float* g = gm + b * 27;
#pragma unroll
    for (int c = 0; c < 3; c++) {
        float rgb = Y0 * g[0 + c] + Y1 * g[3 + c] + Y2 * g[6 + c] + Y3 * g[9 + c] +
                    Y4 * g[12 + c] + Y5 * g[15 + c] + Y6 * g[18 + c] + Y7 * g[21 + c] +
                    Y8 * g[24 + c];
        out_color[ob + c] = rgb * out_color[ob + c];   // in-place: tex -> color
    }
}

__global__ __launch_bounds__(256) void k_landmark(
    const float* __restrict__ out_vertex, const int* __restrict__ keypoints,
    const float* __restrict__ P,   // persc_proj, row-major (3,3)
    float* __restrict__ out_lm)
{
    int t = blockIdx.x * 256 + threadIdx.x;
    if (t >= NB * 68) return;
    int b = t / 68, l = t - b * 68;
    int kp = keypoints[l];
    size_t ob = (size_t)b * NR + 3 * (size_t)kp;
    float x = out_vertex[ob], y = out_vertex[ob + 1], z = out_vertex[ob + 2];
    float p0 = x * P[0] + y * P[3] + z * P[6];
    float p1 = x * P[1] + y * P[4] + z * P[7];
    float p2 = x * P[2] + y * P[5] + z * P[8];
    out_lm[t * 2]     = p0 / p2;
    out_lm[t * 2 + 1] = p1 / p2;
}

extern "C" void kernel_launch(void* const* d_in, const int* in_sizes, int n_in,
                              void* d_out, int out_size, void* d_ws, size_t ws_size,
                              hipStream_t stream) {
    const float* coeffs    = (const float*)d_in[0];
    const float* meanshape = (const float*)d_in[1];
    const float* idBase    = (const float*)d_in[2];
    const float* exBase    = (const float*)d_in[3];
    const float* meantex   = (const float*)d_in[4];
    const float* texBase   = (const float*)d_in[5];
    const float* persc     = (const float*)d_in[6];
    const float* init_lit  = (const float*)d_in[7];
    const int*   point_buf = (const int*)d_in[8];
    const int*   face_buf  = (const int*)d_in[9];
    const int*   keypoints = (const int*)d_in[10];

    float* ws = (float*)d_ws;
    float* rotM  = ws + WS_ROT;
    float* gm    = ws + WS_GM;
    float* ctrS  = ws + WS_CTRS;
    float* ctrT  = ws + WS_CTRT;
    float* shape = ws + WS_SHAPE;

    float* out_vertex = (float*)d_out;
    float* out_color  = out_vertex + (size_t)NB * NR;
    float* out_lm     = out_color  + (size_t)NB * NR;

    k_setup<<<1, 64, 0, stream>>>(coeffs, init_lit, rotM, gm, ctrS, ctrT);

    int gemm_blocks = (NR + 63) / 64;   // 1674
    k_gemm<<<gemm_blocks, 64, 0, stream>>>(idBase, exBase, texBase, meanshape,
                                           meantex, ctrS, ctrT, shape, out_color);

    dim3 g3((N_V + 255) / 256, NB);
    k_vertex<<<g3, 256, 0, stream>>>(shape, rotM, gm, coeffs, point_buf, face_buf,
                                     out_vertex, out_color);

    int lm_blocks = (NB * 68 + 255) / 256;
    k_landmark<<<lm_blocks, 256, 0, stream>>>(out_vertex, keypoints, persc, out_lm);
}

// Round 2
// 394.432 us; speedup vs baseline: 1.5999x; 1.5999x over previous
//
#include <hip/hip_runtime.h>

#define N_V 35709
#define N_F 70789
#define NR  (3*N_V)   // 107127
#define NB  64

// ws layout (floats):
//   rotM  : NB*9   = 576    @ 0
//   gm    : NB*27  = 1728   @ 576
//   ctrS  : 144*NB = 9216   @ 2304   (id+ex coeffs, [j][b])
//   ctrT  : 80*NB  = 5120   @ 11520  (tex coeffs, [j][b])
//   shapeT: NR*64          @ 16640   (pre-rotation face_shape, TRANSPOSED [i][b])
//   texT  : NR*64          @ 16640+NR*64   (texture/255, TRANSPOSED [i][b]) — if ws big enough
#define WS_ROT    0
#define WS_GM     576
#define WS_CTRS   2304
#define WS_CTRT   11520
#define WS_SHAPET 16640

__global__ __launch_bounds__(64) void k_setup(
    const float* __restrict__ coeffs, const float* __restrict__ init_lit,
    float* __restrict__ rotM, float* __restrict__ gm,
    float* __restrict__ ctrS, float* __restrict__ ctrT)
{
    int b = threadIdx.x;
    const float* cb = coeffs + b * 257;

    float ax = cb[224], ay = cb[225], az = cb[226];
    float cx = cosf(ax), sx = sinf(ax);
    float cy = cosf(ay), sy = sinf(ay);
    float cz = cosf(az), sz = sinf(az);
    float m[9];
    m[0] = cz * cy;
    m[1] = cz * sy * sx - sz * cx;
    m[2] = sz * sx + cz * sy * cx;
    m[3] = sz * cy;
    m[4] = cz * cx + sz * sy * sx;
    m[5] = sz * sy * cx - cz * sx;
    m[6] = -sy;
    m[7] = cy * sx;
    m[8] = cy * cx;
#pragma unroll
    for (int k = 0; k < 9; k++) rotM[b * 9 + k] = m[k];

#pragma unroll
    for (int k = 0; k < 9; k++) {
        float il = init_lit[k];
#pragma unroll
        for (int c = 0; c < 3; c++)
            gm[b * 27 + k * 3 + c] = cb[227 + c * 9 + k] + il;
    }

    for (int j = 0; j < 144; j++) ctrS[j * 64 + b] = cb[j];
    for (int j = 0; j < 80; j++)  ctrT[j * 64 + b] = cb[144 + j];
}

__global__ __launch_bounds__(64) void k_gemm(
    const float* __restrict__ idBase, const float* __restrict__ exBase,
    const float* __restrict__ texBase, const float* __restrict__ meanshape,
    const float* __restrict__ meantex,
    const float* __restrict__ ctrS, const float* __restrict__ ctrT,
    float* __restrict__ shapeT,      // ws, [i][64]
    float* __restrict__ texT,        // [i][64] if transposed, else out_color [b][NR]
    int tex_transposed)
{
    int i = blockIdx.x * 64 + threadIdx.x;
    int iv = (i < NR) ? i : (NR - 1);
    const bool ok = (i < NR);

    float2 acc[32];
#pragma unroll
    for (int q = 0; q < 32; q++) { acc[q].x = 0.f; acc[q].y = 0.f; }

    // ---- shape: idBase (80) + exBase (64) ----
    {
        const float4* r4 = (const float4*)(idBase + (size_t)iv * 80);
#pragma unroll 2
        for (int jq = 0; jq < 20; jq++) {
            float4 a4 = r4[jq];
            float as[4] = {a4.x, a4.y, a4.z, a4.w};
#pragma unroll
            for (int s = 0; s < 4; s++) {
                float a = as[s];
                const float2* cp = (const float2*)(ctrS + (jq * 4 + s) * 64);
#pragma unroll
                for (int q = 0; q < 32; q++) {
                    float2 c = cp[q];
                    acc[q].x += a * c.x;
                    acc[q].y += a * c.y;
                }
            }
        }
        const float4* e4 = (const float4*)(exBase + (size_t)iv * 64);
#pragma unroll 2
        for (int jq = 0; jq < 16; jq++) {
            float4 a4 = e4[jq];
            float as[4] = {a4.x, a4.y, a4.z, a4.w};
#pragma unroll
            for (int s = 0; s < 4; s++) {
                float a = as[s];
                const float2* cp = (const float2*)(ctrS + (80 + jq * 4 + s) * 64);
#pragma unroll
                for (int q = 0; q < 32; q++) {
                    float2 c = cp[q];
                    acc[q].x += a * c.x;
                    acc[q].y += a * c.y;
                }
            }
        }
        float ms = meanshape[iv];
        if (ok) {
            float2* so = (float2*)(shapeT + (size_t)i * 64);
#pragma unroll
            for (int q = 0; q < 32; q++)
                so[q] = make_float2(acc[q].x + ms, acc[q].y + ms);
        }
    }

    // ---- texture: texBase (80) ----
#pragma unroll
    for (int q = 0; q < 32; q++) { acc[q].x = 0.f; acc[q].y = 0.f; }
    {
        const float4* t4 = (const float4*)(texBase + (size_t)iv * 80);
#pragma unroll 2
        for (int jq = 0; jq < 20; jq++) {
            float4 a4 = t4[jq];
            float as[4] = {a4.x, a4.y, a4.z, a4.w};
#pragma unroll
            for (int s = 0; s < 4; s++) {
                float a = as[s];
                const float2* cp = (const float2*)(ctrT + (jq * 4 + s) * 64);
#pragma unroll
                for (int q = 0; q < 32; q++) {
                    float2 c = cp[q];
                    acc[q].x += a * c.x;
                    acc[q].y += a * c.y;
                }
            }
        }
        float mt = meantex[iv];
        const float inv255 = 1.0f / 255.0f;
        if (ok) {
            if (tex_transposed) {
                float2* to = (float2*)(texT + (size_t)i * 64);
#pragma unroll
                for (int q = 0; q < 32; q++)
                    to[q] = make_float2((acc[q].x + mt) * inv255, (acc[q].y + mt) * inv255);
            } else {
#pragma unroll
                for (int q = 0; q < 32; q++) {
                    texT[(size_t)(2 * q)     * NR + i] = (acc[q].x + mt) * inv255;
                    texT[(size_t)(2 * q + 1) * NR + i] = (acc[q].y + mt) * inv255;
                }
            }
        }
    }
}

// wave = one vertex for all 64 batches (lane = batch); each wave loops over 8
// consecutive vertices so per-lane rotM/gm loads amortize and scattered output
// writes accumulate to 96 B per lane per wave (merge in L2).
__global__ __launch_bounds__(256) void k_vertex(
    const float* __restrict__ shapeT,  // [i][64]
    const float* __restrict__ texT,    // [i][64] (may be null if tex_in_out)
    const float* __restrict__ rotM, const float* __restrict__ gm,
    const float* __restrict__ coeffs,
    const int* __restrict__ point_buf, const int* __restrict__ face_buf,
    float* __restrict__ out_vertex, float* __restrict__ out_color,
    int tex_in_out)
{
    int wave = threadIdx.x >> 6;
    int b    = threadIdx.x & 63;
    int base = blockIdx.x * 32 + wave * 8;
    if (base >= N_V) return;
    int vend = base + 8; if (vend > N_V) vend = N_V;

    float m0 = rotM[b * 9 + 0], m1 = rotM[b * 9 + 1], m2 = rotM[b * 9 + 2];
    float m3 = rotM[b * 9 + 3], m4 = rotM[b * 9 + 4], m5 = rotM[b * 9 + 5];
    float m6 = rotM[b * 9 + 6], m7 = rotM[b * 9 + 7], m8 = rotM[b * 9 + 8];
    float tx = coeffs[b * 257 + 254], ty = coeffs[b * 257 + 255], tz = coeffs[b * 257 + 256];
    float g[27];
#pragma unroll
    for (int k = 0; k < 27; k++) g[k] = gm[b * 27 + k];

    const float A0C0 = 0.8862269254527580f;
    const float A1C1 = 1.7724538509055159f;
    const float A2C2 = 2.4270323912f;
    const float C6   = 0.7006239022f;
    const float C8   = 1.2135161956f;

    for (int v = base; v < vend; v++) {
        // own (pre-rotation) position — coalesced
        float sx0 = shapeT[(size_t)(3 * v)     * 64 + b];
        float sy0 = shapeT[(size_t)(3 * v + 1) * 64 + b];
        float sz0 = shapeT[(size_t)(3 * v + 2) * 64 + b];

        float vx = m0 * sx0 + m1 * sy0 + m2 * sz0 + tx;
        float vy = m3 * sx0 + m4 * sy0 + m5 * sz0 + ty;
        float vz = m6 * sx0 + m7 * sy0 + m8 * sz0 + tz;

        size_t ob = (size_t)b * NR + 3 * (size_t)v;
        out_vertex[ob]     = vx;
        out_vertex[ob + 1] = vy;
        out_vertex[ob + 2] = 10.0f - vz;

        // vertex normal: 8 faces, indices wave-uniform, data reads coalesced
        float nx = 0.f, ny = 0.f, nz = 0.f;
#pragma unroll
        for (int k = 0; k < 8; k++) {
            int f = point_buf[v * 8 + k];
            if (f < N_F) {
                int i0 = face_buf[f * 3], i1 = face_buf[f * 3 + 1], i2 = face_buf[f * 3 + 2];
                float p0x = shapeT[(size_t)(3 * i0)     * 64 + b];
                float p0y = shapeT[(size_t)(3 * i0 + 1) * 64 + b];
                float p0z = shapeT[(size_t)(3 * i0 + 2) * 64 + b];
                float p1x = shapeT[(size_t)(3 * i1)     * 64 + b];
                float p1y = shapeT[(size_t)(3 * i1 + 1) * 64 + b];
                float p1z = shapeT[(size_t)(3 * i1 + 2) * 64 + b];
                float p2x = shapeT[(size_t)(3 * i2)     * 64 + b];
                float p2y = shapeT[(size_t)(3 * i2 + 1) * 64 + b];
                float p2z = shapeT[(size_t)(3 * i2 + 2) * 64 + b];
                float e1x = p0x - p1x, e1y = p0y - p1y, e1z = p0z - p1z;
                float e2x = p1x - p2x, e2y = p1y - p2y, e2z = p1z - p2z;
                float ccx = e1y * e2z - e1z * e2y;
                float ccy = e1z * e2x - e1x * e2z;
                float ccz = e1x * e2y - e1y * e2x;
                float l = sqrtf(ccx * ccx + ccy * ccy + ccz * ccz);
                float inv = 1.0f / fmaxf(l, 1e-12f);
                nx += ccx * inv; ny += ccy * inv; nz += ccz * inv;
            }
        }
        float l = sqrtf(nx * nx + ny * ny + nz * nz);
        float inv = 1.0f / fmaxf(l, 1e-12f);
        nx *= inv; ny *= inv; nz *= inv;

        float rx = m0 * nx + m1 * ny + m2 * nz;
        float ry = m3 * nx + m4 * ny + m5 * nz;
        float rz = m6 * nx + m7 * ny + m8 * nz;

        float Y0 = A0C0;
        float Y1 = -A1C1 * ry;
        float Y2 =  A1C1 * rz;
        float Y3 = -A1C1 * rx;
        float Y4 =  A2C2 * rx * ry;
        float Y5 = -A2C2 * ry * rz;
        float Y6 =  C6 * (3.f * rz * rz - 1.f);
        float Y7 = -A2C2 * rx * rz;
        float Y8 =  C8 * (rx * rx - ry * ry);

        float t0, t1, t2;
        if (tex_in_out) {
            t0 = out_color[ob]; t1 = out_color[ob + 1]; t2 = out_color[ob + 2];
        } else {
            t0 = texT[(size_t)(3 * v)     * 64 + b];
            t1 = texT[(size_t)(3 * v + 1) * 64 + b];
            t2 = texT[(size_t)(3 * v + 2) * 64 + b];
        }
        float tex3[3] = {t0, t1, t2};
#pragma unroll
        for (int c = 0; c < 3; c++) {
            float rgb = Y0 * g[0 + c] + Y1 * g[3 + c] + Y2 * g[6 + c] + Y3 * g[9 + c] +
                        Y4 * g[12 + c] + Y5 * g[15 + c] + Y6 * g[18 + c] + Y7 * g[21 + c] +
                        Y8 * g[24 + c];
            out_color[ob + c] = rgb * tex3[c];
        }
    }
}

__global__ __launch_bounds__(256) void k_landmark(
    const float* __restrict__ out_vertex, const int* __restrict__ keypoints,
    const float* __restrict__ P,
    float* __restrict__ out_lm)
{
    int t = blockIdx.x * 256 + threadIdx.x;
    if (t >= NB * 68) return;
    int b = t / 68, l = t - b * 68;
    int kp = keypoints[l];
    size_t ob = (size_t)b * NR + 3 * (size_t)kp;
    float x = out_vertex[ob], y = out_vertex[ob + 1], z = out_vertex[ob + 2];
    float p0 = x * P[0] + y * P[3] + z * P[6];
    float p1 = x * P[1] + y * P[4] + z * P[7];
    float p2 = x * P[2] + y * P[5] + z * P[8];
    out_lm[t * 2]     = p0 / p2;
    out_lm[t * 2 + 1] = p1 / p2;
}

extern "C" void kernel_launch(void* const* d_in, const int* in_sizes, int n_in,
                              void* d_out, int out_size, void* d_ws, size_t ws_size,
                              hipStream_t stream) {
    const float* coeffs    = (const float*)d_in[0];
    const float* meanshape = (const float*)d_in[1];
    const float* idBase    = (const float*)d_in[2];
    const float* exBase    = (const float*)d_in[3];
    const float* meantex   = (const float*)d_in[4];
    const float* texBase   = (const float*)d_in[5];
    const float* persc     = (const float*)d_in[6];
    const float* init_lit  = (const float*)d_in[7];
    const int*   point_buf = (const int*)d_in[8];
    const int*   face_buf  = (const int*)d_in[9];
    const int*   keypoints = (const int*)d_in[10];

    float* ws = (float*)d_ws;
    float* rotM   = ws + WS_ROT;
    float* gm     = ws + WS_GM;
    float* ctrS   = ws + WS_CTRS;
    float* ctrT   = ws + WS_CTRT;
    float* shapeT = ws + WS_SHAPET;

    float* out_vertex = (float*)d_out;
    float* out_color  = out_vertex + (size_t)NB * NR;
    float* out_lm     = out_color  + (size_t)NB * NR;

    // texture in transposed ws if it fits, else directly in out_color
    size_t need = ((size_t)WS_SHAPET + 2 * (size_t)NR * 64) * sizeof(float);
    int tex_transposed = (ws_size >= need) ? 1 : 0;
    float* texT = tex_transposed ? (shapeT + (size_t)NR * 64) : out_color;

    k_setup<<<1, 64, 0, stream>>>(coeffs, init_lit, rotM, gm, ctrS, ctrT);

    int gemm_blocks = (NR + 63) / 64;
    k_gemm<<<gemm_blocks, 64, 0, stream>>>(idBase, exBase, texBase, meanshape,
                                           meantex, ctrS, ctrT, shapeT, texT,
                                           tex_transposed);

    int vb = (N_V + 31) / 32;   // 32 vertices per block (4 waves x 8)
    k_vertex<<<vb, 256, 0, stream>>>(shapeT, tex_transposed ? texT : nullptr,
                                     rotM, gm, coeffs, point_buf, face_buf,
                                     out_vertex, out_color, tex_transposed ? 0 : 1);

    int lm_blocks = (NB * 68 + 255) / 256;
    k_landmark<<<lm_blocks, 256, 0, stream>>>(out_vertex, keypoints, persc, out_lm);
}

// Round 3
// 372.206 us; speedup vs baseline: 1.6955x; 1.0597x over previous
//
#include <hip/hip_runtime.h>

#define N_V 35709
#define N_F 70789
#define NR  (3*N_V)   // 107127
#define NB  64

// ws layout (floats):
//   rotM  : NB*9   = 576    @ 0
//   gm    : NB*27  = 1728   @ 576
//   ctrS  : 144*NB = 9216   @ 2304   (id+ex coeffs, [j][b])
//   ctrT  : 80*NB  = 5120   @ 11520  (tex coeffs, [j][b])
//   shapeT: NR*64          @ 16640   (pre-rotation face_shape, TRANSPOSED [i][b])
//   texT  : NR*64          @ 16640+NR*64
#define WS_ROT    0
#define WS_GM     576
#define WS_CTRS   2304
#define WS_CTRT   11520
#define WS_SHAPET 16640

__global__ __launch_bounds__(64) void k_setup_rot(
    const float* __restrict__ coeffs, const float* __restrict__ init_lit,
    float* __restrict__ rotM, float* __restrict__ gm)
{
    int b = threadIdx.x;
    const float* cb = coeffs + b * 257;

    float ax = cb[224], ay = cb[225], az = cb[226];
    float cx = cosf(ax), sx = sinf(ax);
    float cy = cosf(ay), sy = sinf(ay);
    float cz = cosf(az), sz = sinf(az);
    float m[9];
    m[0] = cz * cy;
    m[1] = cz * sy * sx - sz * cx;
    m[2] = sz * sx + cz * sy * cx;
    m[3] = sz * cy;
    m[4] = cz * cx + sz * sy * sx;
    m[5] = sz * sy * cx - cz * sx;
    m[6] = -sy;
    m[7] = cy * sx;
    m[8] = cy * cx;
#pragma unroll
    for (int k = 0; k < 9; k++) rotM[b * 9 + k] = m[k];

#pragma unroll
    for (int k = 0; k < 9; k++) {
        float il = init_lit[k];
#pragma unroll
        for (int c = 0; c < 3; c++)
            gm[b * 27 + k * 3 + c] = cb[227 + c * 9 + k] + il;
    }
}

// grid = 224 blocks of 64: block j transposes coeff column j into [j][b]
__global__ __launch_bounds__(64) void k_transpose(
    const float* __restrict__ coeffs,
    float* __restrict__ ctrS, float* __restrict__ ctrT)
{
    int j = blockIdx.x;
    int b = threadIdx.x;
    float v = coeffs[b * 257 + j];
    if (j < 144) ctrS[j * 64 + b] = v;
    else         ctrT[(j - 144) * 64 + b] = v;
}

// grid (ceil(NR/256), 2): blockIdx.y = batch half. Each wave: 64 rows x 32 batches.
__global__ __launch_bounds__(256) void k_gemm(
    const float* __restrict__ idBase, const float* __restrict__ exBase,
    const float* __restrict__ texBase, const float* __restrict__ meanshape,
    const float* __restrict__ meantex,
    const float* __restrict__ ctrS, const float* __restrict__ ctrT,
    float* __restrict__ shapeT,      // ws, [i][64]
    float* __restrict__ texT,        // [i][64] if transposed, else out_color [b][NR]
    int tex_transposed)
{
    __shared__ float tsh[4][64 * 33];
    int w    = threadIdx.x >> 6;
    int lane = threadIdx.x & 63;
    int h    = blockIdx.y;           // batch half: cols h*32 .. h*32+31
    int i0w  = blockIdx.x * 256 + w * 64;
    int i    = i0w + lane;
    int iv   = (i < NR) ? i : (NR - 1);
    float* sh = tsh[w];

    float acc[32];

    // ---------------- shape ----------------
#pragma unroll
    for (int c = 0; c < 32; c++) acc[c] = 0.f;
    {
        const float4* r4 = (const float4*)(idBase + (size_t)iv * 80);
#pragma unroll 2
        for (int jq = 0; jq < 20; jq++) {
            float4 a4 = r4[jq];
            float as[4] = {a4.x, a4.y, a4.z, a4.w};
#pragma unroll
            for (int s = 0; s < 4; s++) {
                float a = as[s];
                const float4* cp = (const float4*)(ctrS + (jq * 4 + s) * 64 + h * 32);
#pragma unroll
                for (int q = 0; q < 8; q++) {
                    float4 c = cp[q];
                    acc[4 * q + 0] += a * c.x;
                    acc[4 * q + 1] += a * c.y;
                    acc[4 * q + 2] += a * c.z;
                    acc[4 * q + 3] += a * c.w;
                }
            }
        }
        const float4* e4 = (const float4*)(exBase + (size_t)iv * 64);
#pragma unroll 2
        for (int jq = 0; jq < 16; jq++) {
            float4 a4 = e4[jq];
            float as[4] = {a4.x, a4.y, a4.z, a4.w};
#pragma unroll
            for (int s = 0; s < 4; s++) {
                float a = as[s];
                const float4* cp = (const float4*)(ctrS + (80 + jq * 4 + s) * 64 + h * 32);
#pragma unroll
                for (int q = 0; q < 8; q++) {
                    float4 c = cp[q];
                    acc[4 * q + 0] += a * c.x;
                    acc[4 * q + 1] += a * c.y;
                    acc[4 * q + 2] += a * c.z;
                    acc[4 * q + 3] += a * c.w;
                }
            }
        }
        float ms = meanshape[iv];
        // stage: sh[ownerLane*33 + col]
#pragma unroll
        for (int c = 0; c < 32; c++) sh[lane * 33 + c] = acc[c] + ms;
        // flush: row-major coalesced 128-B runs (wave-internal, no barrier)
#pragma unroll 4
        for (int it = 0; it < 32; it++) {
            int r  = it * 2 + (lane >> 5);
            int cb = lane & 31;
            int rg = i0w + r;
            float v = sh[r * 33 + cb];
            if (rg < NR) shapeT[(size_t)rg * 64 + h * 32 + cb] = v;
        }
    }

    // ---------------- texture ----------------
#pragma unroll
    for (int c = 0; c < 32; c++) acc[c] = 0.f;
    {
        const float4* t4 = (const float4*)(texBase + (size_t)iv * 80);
#pragma unroll 2
        for (int jq = 0; jq < 20; jq++) {
            float4 a4 = t4[jq];
            float as[4] = {a4.x, a4.y, a4.z, a4.w};
#pragma unroll
            for (int s = 0; s < 4; s++) {
                float a = as[s];
                const float4* cp = (const float4*)(ctrT + (jq * 4 + s) * 64 + h * 32);
#pragma unroll
                for (int q = 0; q < 8; q++) {
                    float4 c = cp[q];
                    acc[4 * q + 0] += a * c.x;
                    acc[4 * q + 1] += a * c.y;
                    acc[4 * q + 2] += a * c.z;
                    acc[4 * q + 3] += a * c.w;
                }
            }
        }
        float mt = meantex[iv];
        const float inv255 = 1.0f / 255.0f;
        if (tex_transposed) {
#pragma unroll
            for (int c = 0; c < 32; c++) sh[lane * 33 + c] = (acc[c] + mt) * inv255;
#pragma unroll 4
            for (int it = 0; it < 32; it++) {
                int r  = it * 2 + (lane >> 5);
                int cb = lane & 31;
                int rg = i0w + r;
                float v = sh[r * 33 + cb];
                if (rg < NR) texT[(size_t)rg * 64 + h * 32 + cb] = v;
            }
        } else {
            if (i < NR) {
#pragma unroll
                for (int c = 0; c < 32; c++)
                    texT[(size_t)(h * 32 + c) * NR + i] = (acc[c] + mt) * inv255;
            }
        }
    }
}

// wave = one vertex for all 64 batches (lane = batch); 4 waves x 8 vertices per block.
// Outputs staged in LDS, flushed as coalesced nontemporal 256-B runs.
__global__ __launch_bounds__(256) void k_vertex(
    const float* __restrict__ shapeT,  // [i][64]
    const float* __restrict__ texT,    // [i][64] (or null if tex_in_out)
    const float* __restrict__ rotM, const float* __restrict__ gm,
    const float* __restrict__ coeffs,
    const int* __restrict__ point_buf, const int* __restrict__ face_buf,
    float* __restrict__ out_vertex, float* __restrict__ out_color,
    int tex_in_out)
{
    __shared__ float sh[64 * 97];   // [b][96] padded to 97
    int wave = threadIdx.x >> 6;
    int b    = threadIdx.x & 63;
    int v0   = blockIdx.x * 32;
    int nvalid = N_V - v0; if (nvalid > 32) nvalid = 32;
    int kmax = 3 * nvalid;

    float m0 = rotM[b * 9 + 0], m1 = rotM[b * 9 + 1], m2 = rotM[b * 9 + 2];
    float m3 = rotM[b * 9 + 3], m4 = rotM[b * 9 + 4], m5 = rotM[b * 9 + 5];
    float m6 = rotM[b * 9 + 6], m7 = rotM[b * 9 + 7], m8 = rotM[b * 9 + 8];
    float tx = coeffs[b * 257 + 254], ty = coeffs[b * 257 + 255], tz = coeffs[b * 257 + 256];
    float g[27];
#pragma unroll
    for (int k = 0; k < 27; k++) g[k] = gm[b * 27 + k];

    const float A0C0 = 0.8862269254527580f;
    const float A1C1 = 1.7724538509055159f;
    const float A2C2 = 2.4270323912f;
    const float C6   = 0.7006239022f;
    const float C8   = 1.2135161956f;

    float vert[8][3];
    float col[8][3];

#pragma unroll
    for (int vr = 0; vr < 8; vr++) {
        int v = v0 + wave * 8 + vr;
        bool valid = (v < N_V);
        int vc = valid ? v : (N_V - 1);

        float sx0 = shapeT[(size_t)(3 * vc)     * 64 + b];
        float sy0 = shapeT[(size_t)(3 * vc + 1) * 64 + b];
        float sz0 = shapeT[(size_t)(3 * vc + 2) * 64 + b];

        float vx = m0 * sx0 + m1 * sy0 + m2 * sz0 + tx;
        float vy = m3 * sx0 + m4 * sy0 + m5 * sz0 + ty;
        float vz = m6 * sx0 + m7 * sy0 + m8 * sz0 + tz;
        vert[vr][0] = vx; vert[vr][1] = vy; vert[vr][2] = 10.0f - vz;

        float nx = 0.f, ny = 0.f, nz = 0.f;
#pragma unroll
        for (int k = 0; k < 8; k++) {
            int f = point_buf[vc * 8 + k];
            if (f < N_F) {
                int i0 = face_buf[f * 3], i1 = face_buf[f * 3 + 1], i2 = face_buf[f * 3 + 2];
                float p0x = shapeT[(size_t)(3 * i0)     * 64 + b];
                float p0y = shapeT[(size_t)(3 * i0 + 1) * 64 + b];
                float p0z = shapeT[(size_t)(3 * i0 + 2) * 64 + b];
                float p1x = shapeT[(size_t)(3 * i1)     * 64 + b];
                float p1y = shapeT[(size_t)(3 * i1 + 1) * 64 + b];
                float p1z = shapeT[(size_t)(3 * i1 + 2) * 64 + b];
                float p2x = shapeT[(size_t)(3 * i2)     * 64 + b];
                float p2y = shapeT[(size_t)(3 * i2 + 1) * 64 + b];
                float p2z = shapeT[(size_t)(3 * i2 + 2) * 64 + b];
                float e1x = p0x - p1x, e1y = p0y - p1y, e1z = p0z - p1z;
                float e2x = p1x - p2x, e2y = p1y - p2y, e2z = p1z - p2z;
                float ccx = e1y * e2z - e1z * e2y;
                float ccy = e1z * e2x - e1x * e2z;
                float ccz = e1x * e2y - e1y * e2x;
                float l = sqrtf(ccx * ccx + ccy * ccy + ccz * ccz);
                float inv = 1.0f / fmaxf(l, 1e-12f);
                nx += ccx * inv; ny += ccy * inv; nz += ccz * inv;
            }
        }
        float l = sqrtf(nx * nx + ny * ny + nz * nz);
        float inv = 1.0f / fmaxf(l, 1e-12f);
        nx *= inv; ny *= inv; nz *= inv;

        float rx = m0 * nx + m1 * ny + m2 * nz;
        float ry = m3 * nx + m4 * ny + m5 * nz;
        float rz = m6 * nx + m7 * ny + m8 * nz;

        float Y0 = A0C0;
        float Y1 = -A1C1 * ry;
        float Y2 =  A1C1 * rz;
        float Y3 = -A1C1 * rx;
        float Y4 =  A2C2 * rx * ry;
        float Y5 = -A2C2 * ry * rz;
        float Y6 =  C6 * (3.f * rz * rz - 1.f);
        float Y7 = -A2C2 * rx * rz;
        float Y8 =  C8 * (rx * rx - ry * ry);

        float t0, t1, t2;
        if (tex_in_out) {
            size_t ob = (size_t)b * NR + 3 * (size_t)vc;
            t0 = out_color[ob]; t1 = out_color[ob + 1]; t2 = out_color[ob + 2];
        } else {
            t0 = texT[(size_t)(3 * vc)     * 64 + b];
            t1 = texT[(size_t)(3 * vc + 1) * 64 + b];
            t2 = texT[(size_t)(3 * vc + 2) * 64 + b];
        }
        float tex3[3] = {t0, t1, t2};
#pragma unroll
        for (int c = 0; c < 3; c++) {
            float rgb = Y0 * g[0 + c] + Y1 * g[3 + c] + Y2 * g[6 + c] + Y3 * g[9 + c] +
                        Y4 * g[12 + c] + Y5 * g[15 + c] + Y6 * g[18 + c] + Y7 * g[21 + c] +
                        Y8 * g[24 + c];
            col[vr][c] = rgb * tex3[c];
        }
    }

    // ---- stage + flush vertex ----
#pragma unroll
    for (int vr = 0; vr < 8; vr++)
#pragma unroll
        for (int c = 0; c < 3; c++)
            sh[b * 97 + (wave * 8 + vr) * 3 + c] = vert[vr][c];
    __syncthreads();
#pragma unroll 4
    for (int it = 0; it < 24; it++) {
        int f = it * 256 + threadIdx.x;
        int bb = f / 96, k = f - bb * 96;
        if (k < kmax)
            __builtin_nontemporal_store(sh[bb * 97 + k],
                                        out_vertex + (size_t)bb * NR + 3 * (size_t)v0 + k);
    }
    __syncthreads();

    // ---- stage + flush color ----
#pragma unroll
    for (int vr = 0; vr < 8; vr++)
#pragma unroll
        for (int c = 0; c < 3; c++)
            sh[b * 97 + (wave * 8 + vr) * 3 + c] = col[vr][c];
    __syncthreads();
#pragma unroll 4
    for (int it = 0; it < 24; it++) {
        int f = it * 256 + threadIdx.x;
        int bb = f / 96, k = f - bb * 96;
        if (k < kmax)
            __builtin_nontemporal_store(sh[bb * 97 + k],
                                        out_color + (size_t)bb * NR + 3 * (size_t)v0 + k);
    }
}

// grid = 68 blocks of 64 (lane = batch); recompute transform from shapeT
__global__ __launch_bounds__(64) void k_landmark(
    const float* __restrict__ shapeT, const int* __restrict__ keypoints,
    const float* __restrict__ rotM, const float* __restrict__ coeffs,
    const float* __restrict__ P,
    float* __restrict__ out_lm)
{
    int l = blockIdx.x;
    int b = threadIdx.x;
    int kp = keypoints[l];

    float m0 = rotM[b * 9 + 0], m1 = rotM[b * 9 + 1], m2 = rotM[b * 9 + 2];
    float m3 = rotM[b * 9 + 3], m4 = rotM[b * 9 + 4], m5 = rotM[b * 9 + 5];
    float m6 = rotM[b * 9 + 6], m7 = rotM[b * 9 + 7], m8 = rotM[b * 9 + 8];
    float tx = coeffs[b * 257 + 254], ty = coeffs[b * 257 + 255], tz = coeffs[b * 257 + 256];

    float sx0 = shapeT[(size_t)(3 * kp)     * 64 + b];
    float sy0 = shapeT[(size_t)(3 * kp + 1) * 64 + b];
    float sz0 = shapeT[(size_t)(3 * kp + 2) * 64 + b];

    float x = m0 * sx0 + m1 * sy0 + m2 * sz0 + tx;
    float y = m3 * sx0 + m4 * sy0 + m5 * sz0 + ty;
    float z = 10.0f - (m6 * sx0 + m7 * sy0 + m8 * sz0 + tz);

    float p0 = x * P[0] + y * P[3] + z * P[6];
    float p1 = x * P[1] + y * P[4] + z * P[7];
    float p2 = x * P[2] + y * P[5] + z * P[8];

    size_t o = ((size_t)b * 68 + l) * 2;
    out_lm[o]     = p0 / p2;
    out_lm[o + 1] = p1 / p2;
}

extern "C" void kernel_launch(void* const* d_in, const int* in_sizes, int n_in,
                              void* d_out, int out_size, void* d_ws, size_t ws_size,
                              hipStream_t stream) {
    const float* coeffs    = (const float*)d_in[0];
    const float* meanshape = (const float*)d_in[1];
    const float* idBase    = (const float*)d_in[2];
    const float* exBase    = (const float*)d_in[3];
    const float* meantex   = (const float*)d_in[4];
    const float* texBase   = (const float*)d_in[5];
    const float* persc     = (const float*)d_in[6];
    const float* init_lit  = (const float*)d_in[7];
    const int*   point_buf = (const int*)d_in[8];
    const int*   face_buf  = (const int*)d_in[9];
    const int*   keypoints = (const int*)d_in[10];

    float* ws = (float*)d_ws;
    float* rotM   = ws + WS_ROT;
    float* gm     = ws + WS_GM;
    float* ctrS   = ws + WS_CTRS;
    float* ctrT   = ws + WS_CTRT;
    float* shapeT = ws + WS_SHAPET;

    float* out_vertex = (float*)d_out;
    float* out_color  = out_vertex + (size_t)NB * NR;
    float* out_lm     = out_color  + (size_t)NB * NR;

    size_t need = ((size_t)WS_SHAPET + 2 * (size_t)NR * 64) * sizeof(float);
    int tex_transposed = (ws_size >= need) ? 1 : 0;
    float* texT = tex_transposed ? (shapeT + (size_t)NR * 64) : out_color;

    k_setup_rot<<<1, 64, 0, stream>>>(coeffs, init_lit, rotM, gm);
    k_transpose<<<224, 64, 0, stream>>>(coeffs, ctrS, ctrT);

    dim3 gg((NR + 255) / 256, 2);
    k_gemm<<<gg, 256, 0, stream>>>(idBase, exBase, texBase, meanshape,
                                   meantex, ctrS, ctrT, shapeT, texT,
                                   tex_transposed);

    int vb = (N_V + 31) / 32;
    k_vertex<<<vb, 256, 0, stream>>>(shapeT, tex_transposed ? texT : nullptr,
                                     rotM, gm, coeffs, point_buf, face_buf,
                                     out_vertex, out_color, tex_transposed ? 0 : 1);

    k_landmark<<<68, 64, 0, stream>>>(shapeT, keypoints, rotM, coeffs, persc, out_lm);
}